// Round 1
// baseline (393.730 us; speedup 1.0000x reference)
//
#include <hip/hip_runtime.h>
#include <hip/hip_bf16.h>

#define D 128
#define NEG_SLOPE 0.2f

// ---------------- CSR build ----------------

__global__ __launch_bounds__(256) void hist_kernel(const int* __restrict__ ei,
                                                   int* __restrict__ deg, int E, int N) {
  int e = blockIdx.x * 256 + threadIdx.x;
  int total = E + N;
  if (e >= total) return;
  int dst = (e < E) ? ei[E + e] : (e - E);  // self-loops appended at the end
  atomicAdd(&deg[dst], 1);
}

__global__ __launch_bounds__(1024) void scan_kernel(const int* __restrict__ deg,
                                                    int* __restrict__ rowptr, int n) {
  __shared__ int buf[1024];
  int tid = threadIdx.x;
  int carry = 0;
  if (tid == 0) rowptr[0] = 0;
  for (int base = 0; base < n; base += 1024) {
    int i = base + tid;
    int v = (i < n) ? deg[i] : 0;
    buf[tid] = v;
    __syncthreads();
    for (int off = 1; off < 1024; off <<= 1) {
      int t = (tid >= off) ? buf[tid - off] : 0;
      __syncthreads();
      buf[tid] += t;
      __syncthreads();
    }
    if (i < n) rowptr[i + 1] = carry + buf[tid];
    carry += buf[1023];  // safe: last scan step ended with barrier, no writes since
    __syncthreads();     // protect buf before next chunk's store
  }
}

__global__ __launch_bounds__(256) void scatter_kernel(const int* __restrict__ ei,
                                                      const int* __restrict__ rowptr,
                                                      int* __restrict__ cursor,
                                                      int* __restrict__ csr_src, int E, int N) {
  int e = blockIdx.x * 256 + threadIdx.x;
  int total = E + N;
  if (e >= total) return;
  int src, dst;
  if (e < E) { src = ei[e]; dst = ei[E + e]; }
  else       { src = dst = e - E; }
  int pos = rowptr[dst] + atomicAdd(&cursor[dst], 1);
  csr_src[pos] = src;
}

// ---------------- wa = W @ a  (tiny) ----------------

__global__ __launch_bounds__(128) void wa_kernel(const float* __restrict__ W,
                                                 const float* __restrict__ a_s,
                                                 const float* __restrict__ a_d,
                                                 float* __restrict__ wa_s,
                                                 float* __restrict__ wa_d) {
  int k = threadIdx.x;  // 128 threads
  float ss = 0.f, sd = 0.f;
  for (int c = 0; c < D; ++c) {
    float w = W[k * D + c];
    ss += w * a_s[c];
    sd += w * a_d[c];
  }
  wa_s[k] = ss;
  wa_d[k] = sd;
}

// ---------------- alpha_s/d[n] = dot(in[n], wa)  (one wave per row) ----------------

template <bool RELU>
__global__ __launch_bounds__(256) void alpha_kernel(const float* __restrict__ in,
                                                    const float* __restrict__ wa_s,
                                                    const float* __restrict__ wa_d,
                                                    float* __restrict__ as_out,
                                                    float* __restrict__ ad_out, int N) {
  int wave = (blockIdx.x * 256 + threadIdx.x) >> 6;
  int lane = threadIdx.x & 63;
  if (wave >= N) return;
  float x0 = in[(size_t)wave * D + lane];
  float x1 = in[(size_t)wave * D + 64 + lane];
  if (RELU) { x0 = fmaxf(x0, 0.f); x1 = fmaxf(x1, 0.f); }
  float ps = x0 * wa_s[lane] + x1 * wa_s[64 + lane];
  float pd = x0 * wa_d[lane] + x1 * wa_d[64 + lane];
  #pragma unroll
  for (int off = 32; off; off >>= 1) {
    ps += __shfl_down(ps, off);
    pd += __shfl_down(pd, off);
  }
  if (lane == 0) { as_out[wave] = ps; ad_out[wave] = pd; }
}

// ---------------- GEMM: h = (relu?)in @ W  (W + 32-row x tile in LDS) ----------------

template <bool RELU>
__global__ __launch_bounds__(256) void gemm_kernel(const float* __restrict__ in,
                                                   const float* __restrict__ W,
                                                   float* __restrict__ h, int N) {
  __shared__ float Wl[D][D];    // 64 KB
  __shared__ float xl[32][D];   // 16 KB
  int tid = threadIdx.x;
  for (int i = tid * 4; i < D * D; i += 256 * 4) {
    *(float4*)(&Wl[0][0] + i) = *(const float4*)(W + i);
  }
  int row0 = blockIdx.x * 32;
  for (int i = tid * 4; i < 32 * D; i += 256 * 4) {
    int r = i / D, k = i % D;
    float4 v = make_float4(0.f, 0.f, 0.f, 0.f);
    if (row0 + r < N) {
      v = *(const float4*)(in + (size_t)(row0 + r) * D + k);
      if (RELU) {
        v.x = fmaxf(v.x, 0.f); v.y = fmaxf(v.y, 0.f);
        v.z = fmaxf(v.z, 0.f); v.w = fmaxf(v.w, 0.f);
      }
    }
    *(float4*)(&xl[r][k]) = v;
  }
  __syncthreads();

  int ct = tid & 31;   // col-thread: 4 consecutive cols
  int rg = tid >> 5;   // row-group 0..7: rows rg, rg+8, rg+16, rg+24
  int c0 = ct * 4;
  float acc[4][4] = {};
  for (int k = 0; k < D; ++k) {
    float4 w4 = *(const float4*)(&Wl[k][c0]);
    #pragma unroll
    for (int i = 0; i < 4; ++i) {
      float xv = xl[rg + 8 * i][k];
      acc[i][0] += xv * w4.x;
      acc[i][1] += xv * w4.y;
      acc[i][2] += xv * w4.z;
      acc[i][3] += xv * w4.w;
    }
  }
  #pragma unroll
  for (int i = 0; i < 4; ++i) {
    int r = row0 + rg + 8 * i;
    if (r < N)
      *(float4*)(h + (size_t)r * D + c0) =
          make_float4(acc[i][0], acc[i][1], acc[i][2], acc[i][3]);
  }
}

// ---------------- per-dst aggregation: segment softmax + weighted sum ----------------

__global__ __launch_bounds__(64) void agg_kernel(const float* __restrict__ h,
                                                 const int* __restrict__ rowptr,
                                                 const int* __restrict__ csr_src,
                                                 const float* __restrict__ as_,
                                                 const float* __restrict__ ad_,
                                                 const float* __restrict__ bias,
                                                 float* __restrict__ out, int N) {
  int n = blockIdx.x;
  int lane = threadIdx.x;  // 64 lanes, each owns 2 feature dims
  int start = rowptr[n], end = rowptr[n + 1];
  float adv = ad_[n];

  float m = -1e30f;
  for (int e = start; e < end; ++e) {
    int s = csr_src[e];
    float sc = as_[s] + adv;
    sc = sc > 0.f ? sc : NEG_SLOPE * sc;
    m = fmaxf(m, sc);
  }
  float denom = 0.f;
  float2 acc = make_float2(0.f, 0.f);
  for (int e = start; e < end; ++e) {
    int s = csr_src[e];
    float sc = as_[s] + adv;
    sc = sc > 0.f ? sc : NEG_SLOPE * sc;
    float w = __expf(sc - m);
    denom += w;
    float2 hv = *(const float2*)(h + (size_t)s * D + lane * 2);
    acc.x += w * hv.x;
    acc.y += w * hv.y;
  }
  float2 bv = *(const float2*)(bias + lane * 2);
  float inv = 1.f / denom;
  *(float2*)(out + (size_t)n * D + lane * 2) =
      make_float2(acc.x * inv + bv.x, acc.y * inv + bv.y);
}

// ---------------- launch ----------------

extern "C" void kernel_launch(void* const* d_in, const int* in_sizes, int n_in,
                              void* d_out, int out_size, void* d_ws, size_t ws_size,
                              hipStream_t stream) {
  const float* x   = (const float*)d_in[0];
  const int*   ei  = (const int*)d_in[1];
  const float* W1  = (const float*)d_in[2];
  const float* as1 = (const float*)d_in[3];
  const float* ad1 = (const float*)d_in[4];
  const float* b1  = (const float*)d_in[5];
  const float* W2  = (const float*)d_in[6];
  const float* as2 = (const float*)d_in[7];
  const float* ad2 = (const float*)d_in[8];
  const float* b2  = (const float*)d_in[9];

  int N = in_sizes[0] / D;   // 50000
  int E = in_sizes[1] / 2;   // 600000
  int total = E + N;         // edges incl. self-loops

  char* ws = (char*)d_ws;
  size_t off = 0;
  auto alloc = [&](size_t bytes) {
    void* p = ws + off;
    off = (off + bytes + 255) & ~(size_t)255;
    return p;
  };
  float* h       = (float*)alloc((size_t)N * D * sizeof(float));
  float* tmp     = (float*)alloc((size_t)N * D * sizeof(float));
  float* alpha_s = (float*)alloc((size_t)N * sizeof(float));
  float* alpha_d = (float*)alloc((size_t)N * sizeof(float));
  float* wa_s    = (float*)alloc(D * sizeof(float));
  float* wa_d    = (float*)alloc(D * sizeof(float));
  int*   rowptr  = (int*)alloc((size_t)(N + 1) * sizeof(int));
  int*   deg     = (int*)alloc((size_t)N * sizeof(int));
  int*   cursor  = (int*)alloc((size_t)N * sizeof(int));
  int*   csr     = (int*)alloc((size_t)total * sizeof(int));

  // --- CSR by dst (shared by both layers) ---
  hipMemsetAsync(deg, 0, (size_t)N * sizeof(int), stream);
  hipMemsetAsync(cursor, 0, (size_t)N * sizeof(int), stream);
  hist_kernel<<<(total + 255) / 256, 256, 0, stream>>>(ei, deg, E, N);
  scan_kernel<<<1, 1024, 0, stream>>>(deg, rowptr, N);
  scatter_kernel<<<(total + 255) / 256, 256, 0, stream>>>(ei, rowptr, cursor, csr, E, N);

  // --- layer 1 ---
  wa_kernel<<<1, 128, 0, stream>>>(W1, as1, ad1, wa_s, wa_d);
  gemm_kernel<false><<<(N + 31) / 32, 256, 0, stream>>>(x, W1, h, N);
  alpha_kernel<false><<<(N + 3) / 4, 256, 0, stream>>>(x, wa_s, wa_d, alpha_s, alpha_d, N);
  agg_kernel<<<N, 64, 0, stream>>>(h, rowptr, csr, alpha_s, alpha_d, b1, tmp, N);

  // --- layer 2 (relu on input reads) ---
  wa_kernel<<<1, 128, 0, stream>>>(W2, as2, ad2, wa_s, wa_d);
  gemm_kernel<true><<<(N + 31) / 32, 256, 0, stream>>>(tmp, W2, h, N);
  alpha_kernel<true><<<(N + 3) / 4, 256, 0, stream>>>(tmp, wa_s, wa_d, alpha_s, alpha_d, N);
  agg_kernel<<<N, 64, 0, stream>>>(h, rowptr, csr, alpha_s, alpha_d, b2, (float*)d_out, N);
}

// Round 2
// 353.503 us; speedup vs baseline: 1.1138x; 1.1138x over previous
//
#include <hip/hip_runtime.h>
#include <hip/hip_bf16.h>

#define D 128
#define NEG_SLOPE 0.2f
#define AGG_CHUNK 128

// ---------------- CSR build ----------------

__global__ __launch_bounds__(256) void hist_kernel(const int* __restrict__ ei,
                                                   int* __restrict__ deg, int E, int N) {
  int e = blockIdx.x * 256 + threadIdx.x;
  int total = E + N;
  if (e >= total) return;
  int dst = (e < E) ? ei[E + e] : (e - E);  // self-loops appended at the end
  atomicAdd(&deg[dst], 1);
}

// one block, each thread owns a contiguous chunk; 3 barriers total
__global__ __launch_bounds__(1024) void scan_kernel(const int* __restrict__ deg,
                                                    int* __restrict__ rowptr, int n) {
  __shared__ int wsum[16];
  int tid = threadIdx.x;
  int per = (n + 1023) / 1024;
  int s = tid * per;
  int e = min(s + per, n);
  int sum = 0;
  for (int i = s; i < e; ++i) sum += deg[i];
  // wave-level inclusive scan of per-thread sums
  int lane = tid & 63, wid = tid >> 6;
  int v = sum;
  #pragma unroll
  for (int off = 1; off < 64; off <<= 1) {
    int t = __shfl_up(v, off);
    if (lane >= off) v += t;
  }
  if (lane == 63) wsum[wid] = v;
  __syncthreads();
  int wofs = 0;
  #pragma unroll
  for (int w = 0; w < 16; ++w) wofs += (w < wid) ? wsum[w] : 0;
  int run = wofs + v - sum;  // exclusive prefix for this thread's chunk
  for (int i = s; i < e; ++i) { run += deg[i]; rowptr[i + 1] = run; }
  if (tid == 0) rowptr[0] = 0;
}

__global__ __launch_bounds__(256) void scatter_kernel(const int* __restrict__ ei,
                                                      const int* __restrict__ rowptr,
                                                      int* __restrict__ cursor,
                                                      int* __restrict__ csr_src, int E, int N) {
  int e = blockIdx.x * 256 + threadIdx.x;
  int total = E + N;
  if (e >= total) return;
  int src, dst;
  if (e < E) { src = ei[e]; dst = ei[E + e]; }
  else       { src = dst = e - E; }
  int pos = rowptr[dst] + atomicAdd(&cursor[dst], 1);
  csr_src[pos] = src;
}

// ---------------- wa = W @ a  (tiny) ----------------

__global__ __launch_bounds__(128) void wa_kernel(const float* __restrict__ W,
                                                 const float* __restrict__ a_s,
                                                 const float* __restrict__ a_d,
                                                 float* __restrict__ wa_s,
                                                 float* __restrict__ wa_d) {
  int k = threadIdx.x;  // 128 threads
  float ss = 0.f, sd = 0.f;
  for (int c = 0; c < D; ++c) {
    float w = W[k * D + c];
    ss += w * a_s[c];
    sd += w * a_d[c];
  }
  wa_s[k] = ss;
  wa_d[k] = sd;
}

// ---------------- alpha_s/d[n] = dot(in[n], wa)  (one wave per row) ----------------

template <bool RELU>
__global__ __launch_bounds__(256) void alpha_kernel(const float* __restrict__ in,
                                                    const float* __restrict__ wa_s,
                                                    const float* __restrict__ wa_d,
                                                    float* __restrict__ as_out,
                                                    float* __restrict__ ad_out, int N) {
  int wave = (blockIdx.x * 256 + threadIdx.x) >> 6;
  int lane = threadIdx.x & 63;
  if (wave >= N) return;
  float x0 = in[(size_t)wave * D + lane];
  float x1 = in[(size_t)wave * D + 64 + lane];
  if (RELU) { x0 = fmaxf(x0, 0.f); x1 = fmaxf(x1, 0.f); }
  float ps = x0 * wa_s[lane] + x1 * wa_s[64 + lane];
  float pd = x0 * wa_d[lane] + x1 * wa_d[64 + lane];
  #pragma unroll
  for (int off = 32; off; off >>= 1) {
    ps += __shfl_down(ps, off);
    pd += __shfl_down(pd, off);
  }
  if (lane == 0) { as_out[wave] = ps; ad_out[wave] = pd; }
}

// ---------------- GEMM: h = (relu?)in @ W  (k unrolled by 4, all-float4 LDS) ----------------

template <bool RELU>
__global__ __launch_bounds__(256) void gemm_kernel(const float* __restrict__ in,
                                                   const float* __restrict__ W,
                                                   float* __restrict__ h, int N) {
  __shared__ float Wl[D][D];    // 64 KB
  __shared__ float xl[32][D];   // 16 KB
  int tid = threadIdx.x;
  for (int i = tid * 4; i < D * D; i += 256 * 4) {
    *(float4*)(&Wl[0][0] + i) = *(const float4*)(W + i);
  }
  int row0 = blockIdx.x * 32;
  for (int i = tid * 4; i < 32 * D; i += 256 * 4) {
    int r = i / D, k = i % D;
    float4 v = make_float4(0.f, 0.f, 0.f, 0.f);
    if (row0 + r < N) {
      v = *(const float4*)(in + (size_t)(row0 + r) * D + k);
      if (RELU) {
        v.x = fmaxf(v.x, 0.f); v.y = fmaxf(v.y, 0.f);
        v.z = fmaxf(v.z, 0.f); v.w = fmaxf(v.w, 0.f);
      }
    }
    *(float4*)(&xl[r][k]) = v;
  }
  __syncthreads();

  int ct = tid & 31;   // col-thread: 4 consecutive cols
  int rg = tid >> 5;   // row-group 0..7: rows rg, rg+8, rg+16, rg+24
  int c0 = ct * 4;
  float acc[4][4] = {};
  for (int kk = 0; kk < D; kk += 4) {
    float4 w0 = *(const float4*)(&Wl[kk + 0][c0]);
    float4 w1 = *(const float4*)(&Wl[kk + 1][c0]);
    float4 w2 = *(const float4*)(&Wl[kk + 2][c0]);
    float4 w3 = *(const float4*)(&Wl[kk + 3][c0]);
    #pragma unroll
    for (int i = 0; i < 4; ++i) {
      float4 xv = *(const float4*)(&xl[rg + 8 * i][kk]);
      acc[i][0] += xv.x * w0.x + xv.y * w1.x + xv.z * w2.x + xv.w * w3.x;
      acc[i][1] += xv.x * w0.y + xv.y * w1.y + xv.z * w2.y + xv.w * w3.y;
      acc[i][2] += xv.x * w0.z + xv.y * w1.z + xv.z * w2.z + xv.w * w3.z;
      acc[i][3] += xv.x * w0.w + xv.y * w1.w + xv.z * w2.w + xv.w * w3.w;
    }
  }
  #pragma unroll
  for (int i = 0; i < 4; ++i) {
    int r = row0 + rg + 8 * i;
    if (r < N)
      *(float4*)(h + (size_t)r * D + c0) =
          make_float4(acc[i][0], acc[i][1], acc[i][2], acc[i][3]);
  }
}

// ---------------- per-dst aggregation: segment softmax + weighted sum ----------------
// 4 waves/block, one dst node per wave. Lane-parallel score phase; weights
// redistributed via __shfl; feature-parallel h accumulation unrolled x4.

__global__ __launch_bounds__(256) void agg_kernel(const float* __restrict__ h,
                                                  const int* __restrict__ rowptr,
                                                  const int* __restrict__ csr_src,
                                                  const float* __restrict__ as_,
                                                  const float* __restrict__ ad_,
                                                  const float* __restrict__ bias,
                                                  float* __restrict__ out, int N) {
  int wid = threadIdx.x >> 6;
  int lane = threadIdx.x & 63;
  int n = blockIdx.x * 4 + wid;
  if (n >= N) return;
  int start = rowptr[n], end = rowptr[n + 1];
  float adv = ad_[n];

  float m = -1e30f, denom = 0.f;
  float2 acc = make_float2(0.f, 0.f);
  int lane2 = lane * 2;

  for (int cbase = start; cbase < end; cbase += AGG_CHUNK) {
    int cend = min(cbase + AGG_CHUNK, end);
    int cnt = cend - cbase;
    // lane-parallel scores (up to 128 edges: 2 per lane)
    int e0 = cbase + lane, e1 = cbase + 64 + lane;
    int s0 = 0, s1 = 0;
    float sc0 = -1e30f, sc1 = -1e30f;
    if (e0 < cend) {
      s0 = csr_src[e0];
      float sc = as_[s0] + adv;
      sc0 = sc > 0.f ? sc : NEG_SLOPE * sc;
    }
    if (e1 < cend) {
      s1 = csr_src[e1];
      float sc = as_[s1] + adv;
      sc1 = sc > 0.f ? sc : NEG_SLOPE * sc;
    }
    float cm = fmaxf(sc0, sc1);
    #pragma unroll
    for (int off = 32; off; off >>= 1) cm = fmaxf(cm, __shfl_xor(cm, off));
    float mnew = fmaxf(m, cm);
    float rescale = __expf(m - mnew);  // first chunk: exp(-huge) = 0
    denom *= rescale; acc.x *= rescale; acc.y *= rescale;
    m = mnew;
    float w0 = (e0 < cend) ? __expf(sc0 - m) : 0.f;
    float w1 = (e1 < cend) ? __expf(sc1 - m) : 0.f;
    float ps = w0 + w1;
    #pragma unroll
    for (int off = 32; off; off >>= 1) ps += __shfl_xor(ps, off);
    denom += ps;

    // feature-parallel accumulation; s/w broadcast from owning lane via shfl
    int i = 0;
    for (; i + 4 <= cnt; i += 4) {
      int   sA, sB, sC, sD_;
      float wA, wB, wC, wD_;
      if (i + 3 < 64) {
        sA = __shfl(s0, i);     wA = __shfl(w0, i);
        sB = __shfl(s0, i + 1); wB = __shfl(w0, i + 1);
        sC = __shfl(s0, i + 2); wC = __shfl(w0, i + 2);
        sD_ = __shfl(s0, i + 3); wD_ = __shfl(w0, i + 3);
      } else {
        sA = (i     < 64) ? __shfl(s0, i)     : __shfl(s1, i - 64);
        wA = (i     < 64) ? __shfl(w0, i)     : __shfl(w1, i - 64);
        sB = (i + 1 < 64) ? __shfl(s0, i + 1) : __shfl(s1, i - 63);
        wB = (i + 1 < 64) ? __shfl(w0, i + 1) : __shfl(w1, i - 63);
        sC = (i + 2 < 64) ? __shfl(s0, i + 2) : __shfl(s1, i - 62);
        wC = (i + 2 < 64) ? __shfl(w0, i + 2) : __shfl(w1, i - 62);
        sD_ = (i + 3 < 64) ? __shfl(s0, i + 3) : __shfl(s1, i - 61);
        wD_ = (i + 3 < 64) ? __shfl(w0, i + 3) : __shfl(w1, i - 61);
      }
      float2 hA = *(const float2*)(h + (size_t)sA * D + lane2);
      float2 hB = *(const float2*)(h + (size_t)sB * D + lane2);
      float2 hC = *(const float2*)(h + (size_t)sC * D + lane2);
      float2 hD = *(const float2*)(h + (size_t)sD_ * D + lane2);
      acc.x += wA * hA.x + wB * hB.x + wC * hC.x + wD_ * hD.x;
      acc.y += wA * hA.y + wB * hB.y + wC * hC.y + wD_ * hD.y;
    }
    for (; i < cnt; ++i) {
      int   s = (i < 64) ? __shfl(s0, i) : __shfl(s1, i - 64);
      float w = (i < 64) ? __shfl(w0, i) : __shfl(w1, i - 64);
      float2 hv = *(const float2*)(h + (size_t)s * D + lane2);
      acc.x += w * hv.x;
      acc.y += w * hv.y;
    }
  }
  float2 bv = *(const float2*)(bias + lane2);
  float inv = 1.f / denom;
  *(float2*)(out + (size_t)n * D + lane2) =
      make_float2(acc.x * inv + bv.x, acc.y * inv + bv.y);
}

// ---------------- launch ----------------

extern "C" void kernel_launch(void* const* d_in, const int* in_sizes, int n_in,
                              void* d_out, int out_size, void* d_ws, size_t ws_size,
                              hipStream_t stream) {
  const float* x   = (const float*)d_in[0];
  const int*   ei  = (const int*)d_in[1];
  const float* W1  = (const float*)d_in[2];
  const float* as1 = (const float*)d_in[3];
  const float* ad1 = (const float*)d_in[4];
  const float* b1  = (const float*)d_in[5];
  const float* W2  = (const float*)d_in[6];
  const float* as2 = (const float*)d_in[7];
  const float* ad2 = (const float*)d_in[8];
  const float* b2  = (const float*)d_in[9];

  int N = in_sizes[0] / D;   // 50000
  int E = in_sizes[1] / 2;   // 600000
  int total = E + N;         // edges incl. self-loops

  char* ws = (char*)d_ws;
  size_t off = 0;
  auto alloc = [&](size_t bytes) {
    void* p = ws + off;
    off = (off + bytes + 255) & ~(size_t)255;
    return p;
  };
  float* h       = (float*)alloc((size_t)N * D * sizeof(float));
  float* tmp     = (float*)alloc((size_t)N * D * sizeof(float));
  float* alpha_s = (float*)alloc((size_t)N * sizeof(float));
  float* alpha_d = (float*)alloc((size_t)N * sizeof(float));
  float* wa_s    = (float*)alloc(D * sizeof(float));
  float* wa_d    = (float*)alloc(D * sizeof(float));
  int*   rowptr  = (int*)alloc((size_t)(N + 1) * sizeof(int));
  int*   deg     = (int*)alloc((size_t)N * sizeof(int));
  int*   cursor  = (int*)alloc((size_t)N * sizeof(int));
  int*   csr     = (int*)alloc((size_t)total * sizeof(int));

  // --- CSR by dst (shared by both layers) ---
  hipMemsetAsync(deg, 0, (size_t)N * sizeof(int), stream);
  hipMemsetAsync(cursor, 0, (size_t)N * sizeof(int), stream);
  hist_kernel<<<(total + 255) / 256, 256, 0, stream>>>(ei, deg, E, N);
  scan_kernel<<<1, 1024, 0, stream>>>(deg, rowptr, N);
  scatter_kernel<<<(total + 255) / 256, 256, 0, stream>>>(ei, rowptr, cursor, csr, E, N);

  // --- layer 1 ---
  wa_kernel<<<1, 128, 0, stream>>>(W1, as1, ad1, wa_s, wa_d);
  gemm_kernel<false><<<(N + 31) / 32, 256, 0, stream>>>(x, W1, h, N);
  alpha_kernel<false><<<(N + 3) / 4, 256, 0, stream>>>(x, wa_s, wa_d, alpha_s, alpha_d, N);
  agg_kernel<<<(N + 3) / 4, 256, 0, stream>>>(h, rowptr, csr, alpha_s, alpha_d, b1, tmp, N);

  // --- layer 2 (relu on input reads) ---
  wa_kernel<<<1, 128, 0, stream>>>(W2, as2, ad2, wa_s, wa_d);
  gemm_kernel<true><<<(N + 31) / 32, 256, 0, stream>>>(tmp, W2, h, N);
  alpha_kernel<true><<<(N + 3) / 4, 256, 0, stream>>>(tmp, wa_s, wa_d, alpha_s, alpha_d, N);
  agg_kernel<<<(N + 3) / 4, 256, 0, stream>>>(h, rowptr, csr, alpha_s, alpha_d, b2, (float*)d_out, N);
}

// Round 3
// 265.827 us; speedup vs baseline: 1.4812x; 1.3298x over previous
//
#include <hip/hip_runtime.h>
#include <hip/hip_bf16.h>

#define D 128
#define NEG_SLOPE 0.2f
#define AGG_CHUNK 128

// ---------------- CSR build ----------------

__global__ __launch_bounds__(256) void hist_kernel(const int* __restrict__ ei,
                                                   int* __restrict__ deg, int E, int N) {
  int e = blockIdx.x * 256 + threadIdx.x;
  int total = E + N;
  if (e >= total) return;
  int dst = (e < E) ? ei[E + e] : (e - E);  // self-loops appended at the end
  atomicAdd(&deg[dst], 1);
}

// --- hierarchical scan: 1024 elements per block ---

__global__ __launch_bounds__(256) void psum_kernel(const int* __restrict__ deg,
                                                   int* __restrict__ bsum, int n) {
  __shared__ int ws[4];
  int i = blockIdx.x * 1024 + threadIdx.x * 4;
  int4 v = make_int4(0, 0, 0, 0);
  if (i + 3 < n) v = *(const int4*)(deg + i);
  else {
    if (i < n) v.x = deg[i];
    if (i + 1 < n) v.y = deg[i + 1];
    if (i + 2 < n) v.z = deg[i + 2];
    if (i + 3 < n) v.w = deg[i + 3];
  }
  int s = v.x + v.y + v.z + v.w;
  #pragma unroll
  for (int off = 32; off; off >>= 1) s += __shfl_xor(s, off);
  int lane = threadIdx.x & 63, wid = threadIdx.x >> 6;
  if (lane == 0) ws[wid] = s;
  __syncthreads();
  if (threadIdx.x == 0) bsum[blockIdx.x] = ws[0] + ws[1] + ws[2] + ws[3];
}

// single wave: in-place exclusive scan of nb block sums
__global__ __launch_bounds__(64) void bscan_kernel(int* __restrict__ bsum, int nb) {
  int lane = threadIdx.x;
  int carry = 0;
  for (int b = 0; b < nb; b += 64) {
    int i = b + lane;
    int v = (i < nb) ? bsum[i] : 0;
    int incl = v;
    #pragma unroll
    for (int off = 1; off < 64; off <<= 1) {
      int t = __shfl_up(incl, off);
      if (lane >= off) incl += t;
    }
    if (i < nb) bsum[i] = carry + incl - v;  // exclusive
    carry += __shfl(incl, 63);
  }
}

__global__ __launch_bounds__(256) void rowptr_kernel(const int* __restrict__ deg,
                                                     const int* __restrict__ bofs,
                                                     int* __restrict__ rowptr, int n) {
  __shared__ int ws[4];
  int i = blockIdx.x * 1024 + threadIdx.x * 4;
  int4 v = make_int4(0, 0, 0, 0);
  if (i + 3 < n) v = *(const int4*)(deg + i);
  else {
    if (i < n) v.x = deg[i];
    if (i + 1 < n) v.y = deg[i + 1];
    if (i + 2 < n) v.z = deg[i + 2];
    if (i + 3 < n) v.w = deg[i + 3];
  }
  int s = v.x + v.y + v.z + v.w;
  int lane = threadIdx.x & 63, wid = threadIdx.x >> 6;
  int incl = s;
  #pragma unroll
  for (int off = 1; off < 64; off <<= 1) {
    int t = __shfl_up(incl, off);
    if (lane >= off) incl += t;
  }
  if (lane == 63) ws[wid] = incl;
  __syncthreads();
  int wpref = 0;
  #pragma unroll
  for (int w = 0; w < 4; ++w) wpref += (w < wid) ? ws[w] : 0;
  int run = bofs[blockIdx.x] + wpref + incl - s;  // exclusive prefix for element i
  if (i < n)     { run += v.x; rowptr[i + 1] = run; }
  if (i + 1 < n) { run += v.y; rowptr[i + 2] = run; }
  if (i + 2 < n) { run += v.z; rowptr[i + 3] = run; }
  if (i + 3 < n) { run += v.w; rowptr[i + 4] = run; }
  if (blockIdx.x == 0 && threadIdx.x == 0) rowptr[0] = 0;
}

__global__ __launch_bounds__(256) void scatter_kernel(const int* __restrict__ ei,
                                                      const int* __restrict__ rowptr,
                                                      int* __restrict__ cursor,
                                                      int* __restrict__ csr_src,
                                                      int* __restrict__ csr_dst, int E, int N) {
  int e = blockIdx.x * 256 + threadIdx.x;
  int total = E + N;
  if (e >= total) return;
  int src, dst;
  if (e < E) { src = ei[e]; dst = ei[E + e]; }
  else       { src = dst = e - E; }
  int pos = rowptr[dst] + atomicAdd(&cursor[dst], 1);
  csr_src[pos] = src;
  csr_dst[pos] = dst;
}

// ---------------- wa = W @ a  (tiny) ----------------

__global__ __launch_bounds__(128) void wa_kernel(const float* __restrict__ W,
                                                 const float* __restrict__ a_s,
                                                 const float* __restrict__ a_d,
                                                 float* __restrict__ wa_s,
                                                 float* __restrict__ wa_d) {
  int k = threadIdx.x;  // 128 threads
  float ss = 0.f, sd = 0.f;
  for (int c = 0; c < D; ++c) {
    float w = W[k * D + c];
    ss += w * a_s[c];
    sd += w * a_d[c];
  }
  wa_s[k] = ss;
  wa_d[k] = sd;
}

// ---------------- alpha_s/d[n] = dot(in[n], wa)  (one wave per row) ----------------

template <bool RELU>
__global__ __launch_bounds__(256) void alpha_kernel(const float* __restrict__ in,
                                                    const float* __restrict__ wa_s,
                                                    const float* __restrict__ wa_d,
                                                    float* __restrict__ as_out,
                                                    float* __restrict__ ad_out, int N) {
  int wave = (blockIdx.x * 256 + threadIdx.x) >> 6;
  int lane = threadIdx.x & 63;
  if (wave >= N) return;
  float x0 = in[(size_t)wave * D + lane];
  float x1 = in[(size_t)wave * D + 64 + lane];
  if (RELU) { x0 = fmaxf(x0, 0.f); x1 = fmaxf(x1, 0.f); }
  float ps = x0 * wa_s[lane] + x1 * wa_s[64 + lane];
  float pd = x0 * wa_d[lane] + x1 * wa_d[64 + lane];
  #pragma unroll
  for (int off = 32; off; off >>= 1) {
    ps += __shfl_down(ps, off);
    pd += __shfl_down(pd, off);
  }
  if (lane == 0) { as_out[wave] = ps; ad_out[wave] = pd; }
}

// ---------------- per-edge scores (edge-parallel, throughput-bound gathers) ----------

__global__ __launch_bounds__(256) void score_kernel(const int* __restrict__ csr_src,
                                                    const int* __restrict__ csr_dst,
                                                    const float* __restrict__ as_,
                                                    const float* __restrict__ ad_,
                                                    float* __restrict__ escore, int total) {
  int e = blockIdx.x * 256 + threadIdx.x;
  if (e >= total) return;
  float sc = as_[csr_src[e]] + ad_[csr_dst[e]];
  escore[e] = sc > 0.f ? sc : NEG_SLOPE * sc;
}

// ---------------- GEMM: h = (relu?)in @ W -> bf16 out ----------------

template <bool RELU>
__global__ __launch_bounds__(256) void gemm_kernel(const float* __restrict__ in,
                                                   const float* __restrict__ W,
                                                   ushort* __restrict__ hb, int N) {
  __shared__ float Wl[D][D];    // 64 KB
  __shared__ float xl[32][D];   // 16 KB
  int tid = threadIdx.x;
  for (int i = tid * 4; i < D * D; i += 256 * 4) {
    *(float4*)(&Wl[0][0] + i) = *(const float4*)(W + i);
  }
  int row0 = blockIdx.x * 32;
  for (int i = tid * 4; i < 32 * D; i += 256 * 4) {
    int r = i / D, k = i % D;
    float4 v = make_float4(0.f, 0.f, 0.f, 0.f);
    if (row0 + r < N) {
      v = *(const float4*)(in + (size_t)(row0 + r) * D + k);
      if (RELU) {
        v.x = fmaxf(v.x, 0.f); v.y = fmaxf(v.y, 0.f);
        v.z = fmaxf(v.z, 0.f); v.w = fmaxf(v.w, 0.f);
      }
    }
    *(float4*)(&xl[r][k]) = v;
  }
  __syncthreads();

  int ct = tid & 31;   // col-thread: 4 consecutive cols
  int rg = tid >> 5;   // row-group 0..7: rows rg, rg+8, rg+16, rg+24
  int c0 = ct * 4;
  float acc[4][4] = {};
  for (int kk = 0; kk < D; kk += 4) {
    float4 w0 = *(const float4*)(&Wl[kk + 0][c0]);
    float4 w1 = *(const float4*)(&Wl[kk + 1][c0]);
    float4 w2 = *(const float4*)(&Wl[kk + 2][c0]);
    float4 w3 = *(const float4*)(&Wl[kk + 3][c0]);
    #pragma unroll
    for (int i = 0; i < 4; ++i) {
      float4 xv = *(const float4*)(&xl[rg + 8 * i][kk]);
      acc[i][0] += xv.x * w0.x + xv.y * w1.x + xv.z * w2.x + xv.w * w3.x;
      acc[i][1] += xv.x * w0.y + xv.y * w1.y + xv.z * w2.y + xv.w * w3.y;
      acc[i][2] += xv.x * w0.z + xv.y * w1.z + xv.z * w2.z + xv.w * w3.z;
      acc[i][3] += xv.x * w0.w + xv.y * w1.w + xv.z * w2.w + xv.w * w3.w;
    }
  }
  #pragma unroll
  for (int i = 0; i < 4; ++i) {
    int r = row0 + rg + 8 * i;
    if (r < N) {
      ushort4 st;
      __hip_bfloat16 b0 = __float2bfloat16(acc[i][0]);
      __hip_bfloat16 b1 = __float2bfloat16(acc[i][1]);
      __hip_bfloat16 b2 = __float2bfloat16(acc[i][2]);
      __hip_bfloat16 b3 = __float2bfloat16(acc[i][3]);
      st.x = *(ushort*)&b0; st.y = *(ushort*)&b1;
      st.z = *(ushort*)&b2; st.w = *(ushort*)&b3;
      *(ushort4*)(hb + (size_t)r * D + c0) = st;
    }
  }
}

// ---------------- per-dst aggregation: segment softmax + weighted sum ----------------
// 4 waves/block, one dst node per wave. Scores read coalesced from escore;
// h gathered as bf16 (256B/row); weights redistributed via __shfl.

__device__ inline float2 bf2_to_f2(unsigned v) {
  return make_float2(__uint_as_float(v << 16), __uint_as_float(v & 0xffff0000u));
}

__global__ __launch_bounds__(256) void agg_kernel(const unsigned* __restrict__ hb,
                                                  const int* __restrict__ rowptr,
                                                  const int* __restrict__ csr_src,
                                                  const float* __restrict__ escore,
                                                  const float* __restrict__ bias,
                                                  float* __restrict__ out, int N) {
  int wid = threadIdx.x >> 6;
  int lane = threadIdx.x & 63;
  int n = blockIdx.x * 4 + wid;
  if (n >= N) return;
  int start = rowptr[n], end = rowptr[n + 1];

  float m = -1e30f, denom = 0.f;
  float2 acc = make_float2(0.f, 0.f);

  for (int cbase = start; cbase < end; cbase += AGG_CHUNK) {
    int cend = min(cbase + AGG_CHUNK, end);
    int cnt = cend - cbase;
    int e0 = cbase + lane, e1 = cbase + 64 + lane;
    int s0 = 0, s1 = 0;
    float sc0 = -1e30f, sc1 = -1e30f;
    if (e0 < cend) { s0 = csr_src[e0]; sc0 = escore[e0]; }
    if (e1 < cend) { s1 = csr_src[e1]; sc1 = escore[e1]; }
    float cm = fmaxf(sc0, sc1);
    #pragma unroll
    for (int off = 32; off; off >>= 1) cm = fmaxf(cm, __shfl_xor(cm, off));
    float mnew = fmaxf(m, cm);
    float rescale = __expf(m - mnew);  // first chunk: exp(-huge) = 0
    denom *= rescale; acc.x *= rescale; acc.y *= rescale;
    m = mnew;
    float w0 = (e0 < cend) ? __expf(sc0 - m) : 0.f;
    float w1 = (e1 < cend) ? __expf(sc1 - m) : 0.f;
    float ps = w0 + w1;
    #pragma unroll
    for (int off = 32; off; off >>= 1) ps += __shfl_xor(ps, off);
    denom += ps;

    // feature-parallel accumulation; s/w broadcast from owning lane via shfl
    int i = 0;
    for (; i + 4 <= cnt; i += 4) {
      int   sA, sB, sC, sD_;
      float wA, wB, wC, wD_;
      if (i + 3 < 64) {
        sA = __shfl(s0, i);      wA = __shfl(w0, i);
        sB = __shfl(s0, i + 1);  wB = __shfl(w0, i + 1);
        sC = __shfl(s0, i + 2);  wC = __shfl(w0, i + 2);
        sD_ = __shfl(s0, i + 3); wD_ = __shfl(w0, i + 3);
      } else {
        sA = (i     < 64) ? __shfl(s0, i)     : __shfl(s1, i - 64);
        wA = (i     < 64) ? __shfl(w0, i)     : __shfl(w1, i - 64);
        sB = (i + 1 < 64) ? __shfl(s0, i + 1) : __shfl(s1, i - 63);
        wB = (i + 1 < 64) ? __shfl(w0, i + 1) : __shfl(w1, i - 63);
        sC = (i + 2 < 64) ? __shfl(s0, i + 2) : __shfl(s1, i - 62);
        wC = (i + 2 < 64) ? __shfl(w0, i + 2) : __shfl(w1, i - 62);
        sD_ = (i + 3 < 64) ? __shfl(s0, i + 3) : __shfl(s1, i - 61);
        wD_ = (i + 3 < 64) ? __shfl(w0, i + 3) : __shfl(w1, i - 61);
      }
      float2 hA = bf2_to_f2(hb[(size_t)sA * 64 + lane]);
      float2 hB = bf2_to_f2(hb[(size_t)sB * 64 + lane]);
      float2 hC = bf2_to_f2(hb[(size_t)sC * 64 + lane]);
      float2 hD = bf2_to_f2(hb[(size_t)sD_ * 64 + lane]);
      acc.x += wA * hA.x + wB * hB.x + wC * hC.x + wD_ * hD.x;
      acc.y += wA * hA.y + wB * hB.y + wC * hC.y + wD_ * hD.y;
    }
    for (; i < cnt; ++i) {
      int   s = (i < 64) ? __shfl(s0, i) : __shfl(s1, i - 64);
      float w = (i < 64) ? __shfl(w0, i) : __shfl(w1, i - 64);
      float2 hv = bf2_to_f2(hb[(size_t)s * 64 + lane]);
      acc.x += w * hv.x;
      acc.y += w * hv.y;
    }
  }
  float2 bv = *(const float2*)(bias + lane * 2);
  float inv = 1.f / denom;
  *(float2*)(out + (size_t)n * D + lane * 2) =
      make_float2(acc.x * inv + bv.x, acc.y * inv + bv.y);
}

// ---------------- launch ----------------

extern "C" void kernel_launch(void* const* d_in, const int* in_sizes, int n_in,
                              void* d_out, int out_size, void* d_ws, size_t ws_size,
                              hipStream_t stream) {
  const float* x   = (const float*)d_in[0];
  const int*   ei  = (const int*)d_in[1];
  const float* W1  = (const float*)d_in[2];
  const float* as1 = (const float*)d_in[3];
  const float* ad1 = (const float*)d_in[4];
  const float* b1  = (const float*)d_in[5];
  const float* W2  = (const float*)d_in[6];
  const float* as2 = (const float*)d_in[7];
  const float* ad2 = (const float*)d_in[8];
  const float* b2  = (const float*)d_in[9];

  int N = in_sizes[0] / D;   // 50000
  int E = in_sizes[1] / 2;   // 600000
  int total = E + N;         // edges incl. self-loops
  int nb = (N + 1023) / 1024;

  char* ws = (char*)d_ws;
  size_t off = 0;
  auto alloc = [&](size_t bytes) {
    void* p = ws + off;
    off = (off + bytes + 255) & ~(size_t)255;
    return p;
  };
  ushort* hb     = (ushort*)alloc((size_t)N * D * sizeof(ushort));
  float* tmp     = (float*)alloc((size_t)N * D * sizeof(float));
  float* alpha_s = (float*)alloc((size_t)N * sizeof(float));
  float* alpha_d = (float*)alloc((size_t)N * sizeof(float));
  float* wa_s    = (float*)alloc(D * sizeof(float));
  float* wa_d    = (float*)alloc(D * sizeof(float));
  int*   rowptr  = (int*)alloc((size_t)(N + 1) * sizeof(int));
  int*   deg     = (int*)alloc((size_t)N * sizeof(int));
  int*   cursor  = (int*)alloc((size_t)N * sizeof(int));
  int*   bsum    = (int*)alloc((size_t)(nb + 1) * sizeof(int));
  int*   csr     = (int*)alloc((size_t)total * sizeof(int));
  int*   csrd    = (int*)alloc((size_t)total * sizeof(int));
  float* escore  = (float*)alloc((size_t)total * sizeof(float));

  // --- CSR by dst (shared by both layers) ---
  hipMemsetAsync(deg, 0, (size_t)N * sizeof(int), stream);
  hipMemsetAsync(cursor, 0, (size_t)N * sizeof(int), stream);
  hist_kernel<<<(total + 255) / 256, 256, 0, stream>>>(ei, deg, E, N);
  psum_kernel<<<nb, 256, 0, stream>>>(deg, bsum, N);
  bscan_kernel<<<1, 64, 0, stream>>>(bsum, nb);
  rowptr_kernel<<<nb, 256, 0, stream>>>(deg, bsum, rowptr, N);
  scatter_kernel<<<(total + 255) / 256, 256, 0, stream>>>(ei, rowptr, cursor, csr, csrd, E, N);

  // --- layer 1 ---
  wa_kernel<<<1, 128, 0, stream>>>(W1, as1, ad1, wa_s, wa_d);
  gemm_kernel<false><<<(N + 31) / 32, 256, 0, stream>>>(x, W1, hb, N);
  alpha_kernel<false><<<(N + 3) / 4, 256, 0, stream>>>(x, wa_s, wa_d, alpha_s, alpha_d, N);
  score_kernel<<<(total + 255) / 256, 256, 0, stream>>>(csr, csrd, alpha_s, alpha_d, escore, total);
  agg_kernel<<<(N + 3) / 4, 256, 0, stream>>>((const unsigned*)hb, rowptr, csr, escore, b1, tmp, N);

  // --- layer 2 (relu on input reads) ---
  wa_kernel<<<1, 128, 0, stream>>>(W2, as2, ad2, wa_s, wa_d);
  gemm_kernel<true><<<(N + 31) / 32, 256, 0, stream>>>(tmp, W2, hb, N);
  alpha_kernel<true><<<(N + 3) / 4, 256, 0, stream>>>(tmp, wa_s, wa_d, alpha_s, alpha_d, N);
  score_kernel<<<(total + 255) / 256, 256, 0, stream>>>(csr, csrd, alpha_s, alpha_d, escore, total);
  agg_kernel<<<(N + 3) / 4, 256, 0, stream>>>((const unsigned*)hb, rowptr, csr, escore, b2, (float*)d_out, N);
}

// Round 4
// 216.275 us; speedup vs baseline: 1.8205x; 1.2291x over previous
//
#include <hip/hip_runtime.h>
#include <hip/hip_bf16.h>

#define D 128
#define NEG_SLOPE 0.2f
#define AGG_CHUNK 128
#define CHUNKB 4096  // edges per block in bucket passes

// ================= CSR build: two-level LDS counting sort =================
// Edge id space e in [0, total): e < E -> (ei[e], ei[E+e]); else self-loop (e-E, e-E).
// Coarse bucket = dst >> 8 (nbkt buckets). Packed edge word = src | (dst << 16).

__global__ __launch_bounds__(256) void bucket_count_kernel(const int* __restrict__ ei,
                                                           int* __restrict__ coarse,
                                                           int E, int total, int nbkt, int nblk) {
  __shared__ int hist[256];
  for (int i = threadIdx.x; i < nbkt; i += 256) hist[i] = 0;
  __syncthreads();
  int base = blockIdx.x * CHUNKB;
  int end = min(base + CHUNKB, total);
  for (int e = base + threadIdx.x; e < end; e += 256) {
    int dst = (e < E) ? ei[E + e] : (e - E);
    atomicAdd(&hist[dst >> 8], 1);
  }
  __syncthreads();
  for (int i = threadIdx.x; i < nbkt; i += 256)
    coarse[(size_t)i * nblk + blockIdx.x] = hist[i];
}

__global__ __launch_bounds__(256) void bucket_scatter_kernel(const int* __restrict__ ei,
                                                             const int* __restrict__ scanout,
                                                             int* __restrict__ stage,
                                                             int E, int total, int nbkt, int nblk) {
  __shared__ int cur[256];
  for (int i = threadIdx.x; i < nbkt; i += 256)
    cur[i] = scanout[(size_t)i * nblk + blockIdx.x];
  __syncthreads();
  int base = blockIdx.x * CHUNKB;
  int end = min(base + CHUNKB, total);
  for (int e = base + threadIdx.x; e < end; e += 256) {
    int src, dst;
    if (e < E) { src = ei[e]; dst = ei[E + e]; }
    else       { src = dst = e - E; }
    int pos = atomicAdd(&cur[dst >> 8], 1);
    stage[pos] = src | (dst << 16);
  }
}

// one block per coarse bucket: fine counting sort + rowptr emission
__global__ __launch_bounds__(256) void fine_sort_kernel(const int* __restrict__ stage,
                                                        const int* __restrict__ scanout,
                                                        unsigned* __restrict__ csr,
                                                        int* __restrict__ rowptr,
                                                        int N, int nblk) {
  __shared__ int cnt[256];
  __shared__ int ofs[256];
  __shared__ int wsum[4];
  int b = blockIdx.x;
  int tid = threadIdx.x;
  int rbase = scanout[(size_t)b * nblk];
  int rend = scanout[(size_t)(b + 1) * nblk];
  cnt[tid] = 0;
  __syncthreads();
  for (int e = rbase + tid; e < rend; e += 256)
    atomicAdd(&cnt[((unsigned)stage[e] >> 16) & 255u], 1);
  __syncthreads();
  int v = cnt[tid];
  int lane = tid & 63, wid = tid >> 6;
  int incl = v;
  #pragma unroll
  for (int off = 1; off < 64; off <<= 1) {
    int t = __shfl_up(incl, off);
    if (lane >= off) incl += t;
  }
  if (lane == 63) wsum[wid] = incl;
  __syncthreads();
  int wpref = 0;
  #pragma unroll
  for (int w = 0; w < 4; ++w) wpref += (w < wid) ? wsum[w] : 0;
  int excl = wpref + incl - v;
  ofs[tid] = excl;
  cnt[tid] = 0;  // reuse as cursor (only ever read by own thread before this)
  int n = b * 256 + tid;
  if (n < N) rowptr[n] = rbase + excl;
  if (b == gridDim.x - 1 && tid == 0) rowptr[N] = rend;
  __syncthreads();
  for (int e = rbase + tid; e < rend; e += 256) {
    unsigned p = (unsigned)stage[e];
    int j = (int)((p >> 16) & 255u);
    int pos = rbase + ofs[j] + atomicAdd(&cnt[j], 1);
    csr[pos] = p;
  }
}

// --- hierarchical scan (generic int array) ---

__global__ __launch_bounds__(256) void psum_kernel(const int* __restrict__ deg,
                                                   int* __restrict__ bsum, int n) {
  __shared__ int ws[4];
  int i = blockIdx.x * 1024 + threadIdx.x * 4;
  int4 v = make_int4(0, 0, 0, 0);
  if (i + 3 < n) v = *(const int4*)(deg + i);
  else {
    if (i < n) v.x = deg[i];
    if (i + 1 < n) v.y = deg[i + 1];
    if (i + 2 < n) v.z = deg[i + 2];
    if (i + 3 < n) v.w = deg[i + 3];
  }
  int s = v.x + v.y + v.z + v.w;
  #pragma unroll
  for (int off = 32; off; off >>= 1) s += __shfl_xor(s, off);
  int lane = threadIdx.x & 63, wid = threadIdx.x >> 6;
  if (lane == 0) ws[wid] = s;
  __syncthreads();
  if (threadIdx.x == 0) bsum[blockIdx.x] = ws[0] + ws[1] + ws[2] + ws[3];
}

__global__ __launch_bounds__(64) void bscan_kernel(int* __restrict__ bsum, int nb) {
  int lane = threadIdx.x;
  int carry = 0;
  for (int b = 0; b < nb; b += 64) {
    int i = b + lane;
    int v = (i < nb) ? bsum[i] : 0;
    int incl = v;
    #pragma unroll
    for (int off = 1; off < 64; off <<= 1) {
      int t = __shfl_up(incl, off);
      if (lane >= off) incl += t;
    }
    if (i < nb) bsum[i] = carry + incl - v;  // exclusive
    carry += __shfl(incl, 63);
  }
}

__global__ __launch_bounds__(256) void rowptr_kernel(const int* __restrict__ deg,
                                                     const int* __restrict__ bofs,
                                                     int* __restrict__ rowptr, int n) {
  __shared__ int ws[4];
  int i = blockIdx.x * 1024 + threadIdx.x * 4;
  int4 v = make_int4(0, 0, 0, 0);
  if (i + 3 < n) v = *(const int4*)(deg + i);
  else {
    if (i < n) v.x = deg[i];
    if (i + 1 < n) v.y = deg[i + 1];
    if (i + 2 < n) v.z = deg[i + 2];
    if (i + 3 < n) v.w = deg[i + 3];
  }
  int s = v.x + v.y + v.z + v.w;
  int lane = threadIdx.x & 63, wid = threadIdx.x >> 6;
  int incl = s;
  #pragma unroll
  for (int off = 1; off < 64; off <<= 1) {
    int t = __shfl_up(incl, off);
    if (lane >= off) incl += t;
  }
  if (lane == 63) ws[wid] = incl;
  __syncthreads();
  int wpref = 0;
  #pragma unroll
  for (int w = 0; w < 4; ++w) wpref += (w < wid) ? ws[w] : 0;
  int run = bofs[blockIdx.x] + wpref + incl - s;
  if (i < n)     { run += v.x; rowptr[i + 1] = run; }
  if (i + 1 < n) { run += v.y; rowptr[i + 2] = run; }
  if (i + 2 < n) { run += v.z; rowptr[i + 3] = run; }
  if (i + 3 < n) { run += v.w; rowptr[i + 4] = run; }
  if (blockIdx.x == 0 && threadIdx.x == 0) rowptr[0] = 0;
}

// ================= dense phase =================

__global__ __launch_bounds__(128) void wa_kernel(const float* __restrict__ W,
                                                 const float* __restrict__ a_s,
                                                 const float* __restrict__ a_d,
                                                 float* __restrict__ wa_s,
                                                 float* __restrict__ wa_d) {
  int k = threadIdx.x;
  float ss = 0.f, sd = 0.f;
  for (int c = 0; c < D; ++c) {
    float w = W[k * D + c];
    ss += w * a_s[c];
    sd += w * a_d[c];
  }
  wa_s[k] = ss;
  wa_d[k] = sd;
}

template <bool RELU>
__global__ __launch_bounds__(256) void alpha_kernel(const float* __restrict__ in,
                                                    const float* __restrict__ wa_s,
                                                    const float* __restrict__ wa_d,
                                                    float* __restrict__ as_out,
                                                    float* __restrict__ ad_out, int N) {
  int wave = (blockIdx.x * 256 + threadIdx.x) >> 6;
  int lane = threadIdx.x & 63;
  if (wave >= N) return;
  float x0 = in[(size_t)wave * D + lane];
  float x1 = in[(size_t)wave * D + 64 + lane];
  if (RELU) { x0 = fmaxf(x0, 0.f); x1 = fmaxf(x1, 0.f); }
  float ps = x0 * wa_s[lane] + x1 * wa_s[64 + lane];
  float pd = x0 * wa_d[lane] + x1 * wa_d[64 + lane];
  #pragma unroll
  for (int off = 32; off; off >>= 1) {
    ps += __shfl_down(ps, off);
    pd += __shfl_down(pd, off);
  }
  if (lane == 0) { as_out[wave] = ps; ad_out[wave] = pd; }
}

__global__ __launch_bounds__(256) void score_kernel(const unsigned* __restrict__ csr,
                                                    const float* __restrict__ as_,
                                                    const float* __restrict__ ad_,
                                                    float* __restrict__ escore, int total) {
  int e = blockIdx.x * 256 + threadIdx.x;
  if (e >= total) return;
  unsigned p = csr[e];
  float sc = as_[p & 0xffffu] + ad_[p >> 16];
  escore[e] = sc > 0.f ? sc : NEG_SLOPE * sc;
}

template <bool RELU>
__global__ __launch_bounds__(256) void gemm_kernel(const float* __restrict__ in,
                                                   const float* __restrict__ W,
                                                   ushort* __restrict__ hb, int N) {
  __shared__ float Wl[D][D];
  __shared__ float xl[32][D];
  int tid = threadIdx.x;
  for (int i = tid * 4; i < D * D; i += 256 * 4)
    *(float4*)(&Wl[0][0] + i) = *(const float4*)(W + i);
  int row0 = blockIdx.x * 32;
  for (int i = tid * 4; i < 32 * D; i += 256 * 4) {
    int r = i / D, k = i % D;
    float4 v = make_float4(0.f, 0.f, 0.f, 0.f);
    if (row0 + r < N) {
      v = *(const float4*)(in + (size_t)(row0 + r) * D + k);
      if (RELU) {
        v.x = fmaxf(v.x, 0.f); v.y = fmaxf(v.y, 0.f);
        v.z = fmaxf(v.z, 0.f); v.w = fmaxf(v.w, 0.f);
      }
    }
    *(float4*)(&xl[r][k]) = v;
  }
  __syncthreads();

  int ct = tid & 31;
  int rg = tid >> 5;
  int c0 = ct * 4;
  float acc[4][4] = {};
  for (int kk = 0; kk < D; kk += 4) {
    float4 w0 = *(const float4*)(&Wl[kk + 0][c0]);
    float4 w1 = *(const float4*)(&Wl[kk + 1][c0]);
    float4 w2 = *(const float4*)(&Wl[kk + 2][c0]);
    float4 w3 = *(const float4*)(&Wl[kk + 3][c0]);
    #pragma unroll
    for (int i = 0; i < 4; ++i) {
      float4 xv = *(const float4*)(&xl[rg + 8 * i][kk]);
      acc[i][0] += xv.x * w0.x + xv.y * w1.x + xv.z * w2.x + xv.w * w3.x;
      acc[i][1] += xv.x * w0.y + xv.y * w1.y + xv.z * w2.y + xv.w * w3.y;
      acc[i][2] += xv.x * w0.z + xv.y * w1.z + xv.z * w2.z + xv.w * w3.z;
      acc[i][3] += xv.x * w0.w + xv.y * w1.w + xv.z * w2.w + xv.w * w3.w;
    }
  }
  #pragma unroll
  for (int i = 0; i < 4; ++i) {
    int r = row0 + rg + 8 * i;
    if (r < N) {
      ushort4 st;
      __hip_bfloat16 b0 = __float2bfloat16(acc[i][0]);
      __hip_bfloat16 b1 = __float2bfloat16(acc[i][1]);
      __hip_bfloat16 b2 = __float2bfloat16(acc[i][2]);
      __hip_bfloat16 b3 = __float2bfloat16(acc[i][3]);
      st.x = *(ushort*)&b0; st.y = *(ushort*)&b1;
      st.z = *(ushort*)&b2; st.w = *(ushort*)&b3;
      *(ushort4*)(hb + (size_t)r * D + c0) = st;
    }
  }
}

// ================= per-dst aggregation =================

__device__ inline float2 bf2_to_f2(unsigned v) {
  return make_float2(__uint_as_float(v << 16), __uint_as_float(v & 0xffff0000u));
}

__global__ __launch_bounds__(256) void agg_kernel(const unsigned* __restrict__ hb,
                                                  const int* __restrict__ rowptr,
                                                  const unsigned* __restrict__ csr,
                                                  const float* __restrict__ escore,
                                                  const float* __restrict__ bias,
                                                  float* __restrict__ out, int N) {
  int wid = threadIdx.x >> 6;
  int lane = threadIdx.x & 63;
  int n = blockIdx.x * 4 + wid;
  if (n >= N) return;
  int start = rowptr[n], end = rowptr[n + 1];

  float m = -1e30f, denom = 0.f;
  float2 acc = make_float2(0.f, 0.f);

  for (int cbase = start; cbase < end; cbase += AGG_CHUNK) {
    int cend = min(cbase + AGG_CHUNK, end);
    int cnt = cend - cbase;
    int e0 = cbase + lane, e1 = cbase + 64 + lane;
    int s0 = 0, s1 = 0;
    float sc0 = -1e30f, sc1 = -1e30f;
    if (e0 < cend) { s0 = (int)(csr[e0] & 0xffffu); sc0 = escore[e0]; }
    if (e1 < cend) { s1 = (int)(csr[e1] & 0xffffu); sc1 = escore[e1]; }
    float cm = fmaxf(sc0, sc1);
    #pragma unroll
    for (int off = 32; off; off >>= 1) cm = fmaxf(cm, __shfl_xor(cm, off));
    float mnew = fmaxf(m, cm);
    float rescale = __expf(m - mnew);
    denom *= rescale; acc.x *= rescale; acc.y *= rescale;
    m = mnew;
    float w0 = (e0 < cend) ? __expf(sc0 - m) : 0.f;
    float w1 = (e1 < cend) ? __expf(sc1 - m) : 0.f;
    float ps = w0 + w1;
    #pragma unroll
    for (int off = 32; off; off >>= 1) ps += __shfl_xor(ps, off);
    denom += ps;

    int i = 0;
    for (; i + 4 <= cnt; i += 4) {
      int   sA, sB, sC, sD_;
      float wA, wB, wC, wD_;
      if (i + 3 < 64) {
        sA = __shfl(s0, i);      wA = __shfl(w0, i);
        sB = __shfl(s0, i + 1);  wB = __shfl(w0, i + 1);
        sC = __shfl(s0, i + 2);  wC = __shfl(w0, i + 2);
        sD_ = __shfl(s0, i + 3); wD_ = __shfl(w0, i + 3);
      } else {
        sA = (i     < 64) ? __shfl(s0, i)     : __shfl(s1, i - 64);
        wA = (i     < 64) ? __shfl(w0, i)     : __shfl(w1, i - 64);
        sB = (i + 1 < 64) ? __shfl(s0, i + 1) : __shfl(s1, i - 63);
        wB = (i + 1 < 64) ? __shfl(w0, i + 1) : __shfl(w1, i - 63);
        sC = (i + 2 < 64) ? __shfl(s0, i + 2) : __shfl(s1, i - 62);
        wC = (i + 2 < 64) ? __shfl(w0, i + 2) : __shfl(w1, i - 62);
        sD_ = (i + 3 < 64) ? __shfl(s0, i + 3) : __shfl(s1, i - 61);
        wD_ = (i + 3 < 64) ? __shfl(w0, i + 3) : __shfl(w1, i - 61);
      }
      float2 hA = bf2_to_f2(hb[(size_t)sA * 64 + lane]);
      float2 hB = bf2_to_f2(hb[(size_t)sB * 64 + lane]);
      float2 hC = bf2_to_f2(hb[(size_t)sC * 64 + lane]);
      float2 hD = bf2_to_f2(hb[(size_t)sD_ * 64 + lane]);
      acc.x += wA * hA.x + wB * hB.x + wC * hC.x + wD_ * hD.x;
      acc.y += wA * hA.y + wB * hB.y + wC * hC.y + wD_ * hD.y;
    }
    for (; i < cnt; ++i) {
      int   s = (i < 64) ? __shfl(s0, i) : __shfl(s1, i - 64);
      float w = (i < 64) ? __shfl(w0, i) : __shfl(w1, i - 64);
      float2 hv = bf2_to_f2(hb[(size_t)s * 64 + lane]);
      acc.x += w * hv.x;
      acc.y += w * hv.y;
    }
  }
  float2 bv = *(const float2*)(bias + lane * 2);
  float inv = 1.f / denom;
  *(float2*)(out + (size_t)n * D + lane * 2) =
      make_float2(acc.x * inv + bv.x, acc.y * inv + bv.y);
}

// ================= launch =================

extern "C" void kernel_launch(void* const* d_in, const int* in_sizes, int n_in,
                              void* d_out, int out_size, void* d_ws, size_t ws_size,
                              hipStream_t stream) {
  const float* x   = (const float*)d_in[0];
  const int*   ei  = (const int*)d_in[1];
  const float* W1  = (const float*)d_in[2];
  const float* as1 = (const float*)d_in[3];
  const float* ad1 = (const float*)d_in[4];
  const float* b1  = (const float*)d_in[5];
  const float* W2  = (const float*)d_in[6];
  const float* as2 = (const float*)d_in[7];
  const float* ad2 = (const float*)d_in[8];
  const float* b2  = (const float*)d_in[9];

  int N = in_sizes[0] / D;        // 50000
  int E = in_sizes[1] / 2;        // 600000
  int total = E + N;              // edges incl. self-loops
  int nbkt = (N + 255) >> 8;      // coarse buckets (<=256; N<65536 guaranteed here)
  int nblk = (total + CHUNKB - 1) / CHUNKB;
  int nscan = nbkt * nblk;
  int nsb = (nscan + 1023) / 1024;

  char* ws = (char*)d_ws;
  size_t off = 0;
  auto alloc = [&](size_t bytes) {
    void* p = ws + off;
    off = (off + bytes + 255) & ~(size_t)255;
    return p;
  };
  ushort*   hb      = (ushort*)alloc((size_t)N * D * sizeof(ushort));
  float*    tmp     = (float*)alloc((size_t)N * D * sizeof(float));
  float*    alpha_s = (float*)alloc((size_t)N * sizeof(float));
  float*    alpha_d = (float*)alloc((size_t)N * sizeof(float));
  float*    wa_s    = (float*)alloc(D * sizeof(float));
  float*    wa_d    = (float*)alloc(D * sizeof(float));
  int*      rowptr  = (int*)alloc((size_t)(N + 1) * sizeof(int));
  int*      coarse  = (int*)alloc((size_t)nscan * sizeof(int));
  int*      scanout = (int*)alloc((size_t)(nscan + 1) * sizeof(int));
  int*      bsum    = (int*)alloc((size_t)(nsb + 1) * sizeof(int));
  int*      stage   = (int*)alloc((size_t)total * sizeof(int));
  unsigned* csr     = (unsigned*)alloc((size_t)total * sizeof(unsigned));
  float*    escore  = (float*)alloc((size_t)total * sizeof(float));

  // --- CSR by dst via two-level counting sort (shared by both layers) ---
  bucket_count_kernel<<<nblk, 256, 0, stream>>>(ei, coarse, E, total, nbkt, nblk);
  psum_kernel<<<nsb, 256, 0, stream>>>(coarse, bsum, nscan);
  bscan_kernel<<<1, 64, 0, stream>>>(bsum, nsb);
  rowptr_kernel<<<nsb, 256, 0, stream>>>(coarse, bsum, scanout, nscan);
  bucket_scatter_kernel<<<nblk, 256, 0, stream>>>(ei, scanout, stage, E, total, nbkt, nblk);
  fine_sort_kernel<<<nbkt, 256, 0, stream>>>(stage, scanout, csr, rowptr, N, nblk);

  // --- layer 1 ---
  wa_kernel<<<1, 128, 0, stream>>>(W1, as1, ad1, wa_s, wa_d);
  gemm_kernel<false><<<(N + 31) / 32, 256, 0, stream>>>(x, W1, hb, N);
  alpha_kernel<false><<<(N + 3) / 4, 256, 0, stream>>>(x, wa_s, wa_d, alpha_s, alpha_d, N);
  score_kernel<<<(total + 255) / 256, 256, 0, stream>>>(csr, alpha_s, alpha_d, escore, total);
  agg_kernel<<<(N + 3) / 4, 256, 0, stream>>>((const unsigned*)hb, rowptr, csr, escore, b1, tmp, N);

  // --- layer 2 (relu on input reads) ---
  wa_kernel<<<1, 128, 0, stream>>>(W2, as2, ad2, wa_s, wa_d);
  gemm_kernel<true><<<(N + 31) / 32, 256, 0, stream>>>(tmp, W2, hb, N);
  alpha_kernel<true><<<(N + 3) / 4, 256, 0, stream>>>(tmp, wa_s, wa_d, alpha_s, alpha_d, N);
  score_kernel<<<(total + 255) / 256, 256, 0, stream>>>(csr, alpha_s, alpha_d, escore, total);
  agg_kernel<<<(N + 3) / 4, 256, 0, stream>>>((const unsigned*)hb, rowptr, csr, escore, b2, (float*)d_out, N);
}

// Round 5
// 147.214 us; speedup vs baseline: 2.6745x; 1.4691x over previous
//
#include <hip/hip_runtime.h>
#include <hip/hip_bf16.h>

#define D 128
#define NEG_SLOPE 0.2f
#define AGG_CHUNK 128
#define CHUNKB 4096  // edges per block in bucket passes

typedef short bf16x8 __attribute__((ext_vector_type(8)));
typedef float f32x4 __attribute__((ext_vector_type(4)));

__device__ inline unsigned short bfbits(float f) {
  __hip_bfloat16 b = __float2bfloat16(f);
  return *(unsigned short*)&b;
}

// ================= CSR build: two-level LDS counting sort =================

__global__ __launch_bounds__(256) void bucket_count_kernel(const int* __restrict__ ei,
                                                           int* __restrict__ coarse,
                                                           int E, int total, int nbkt, int nblk) {
  __shared__ int hist[256];
  for (int i = threadIdx.x; i < nbkt; i += 256) hist[i] = 0;
  __syncthreads();
  int base = blockIdx.x * CHUNKB;
  int end = min(base + CHUNKB, total);
  for (int e = base + threadIdx.x; e < end; e += 256) {
    int dst = (e < E) ? ei[E + e] : (e - E);
    atomicAdd(&hist[dst >> 8], 1);
  }
  __syncthreads();
  for (int i = threadIdx.x; i < nbkt; i += 256)
    coarse[(size_t)i * nblk + blockIdx.x] = hist[i];
}

__global__ __launch_bounds__(256) void bucket_scatter_kernel(const int* __restrict__ ei,
                                                             const int* __restrict__ scanout,
                                                             int* __restrict__ stage,
                                                             int E, int total, int nbkt, int nblk) {
  __shared__ int cur[256];
  for (int i = threadIdx.x; i < nbkt; i += 256)
    cur[i] = scanout[(size_t)i * nblk + blockIdx.x];
  __syncthreads();
  int base = blockIdx.x * CHUNKB;
  int end = min(base + CHUNKB, total);
  for (int e = base + threadIdx.x; e < end; e += 256) {
    int src, dst;
    if (e < E) { src = ei[e]; dst = ei[E + e]; }
    else       { src = dst = e - E; }
    int pos = atomicAdd(&cur[dst >> 8], 1);
    stage[pos] = src | (dst << 16);
  }
}

__global__ __launch_bounds__(256) void fine_sort_kernel(const int* __restrict__ stage,
                                                        const int* __restrict__ scanout,
                                                        unsigned* __restrict__ csr,
                                                        int* __restrict__ rowptr,
                                                        int N, int nblk) {
  __shared__ int cnt[256];
  __shared__ int ofs[256];
  __shared__ int wsum[4];
  int b = blockIdx.x;
  int tid = threadIdx.x;
  int rbase = scanout[(size_t)b * nblk];
  int rend = scanout[(size_t)(b + 1) * nblk];
  cnt[tid] = 0;
  __syncthreads();
  for (int e = rbase + tid; e < rend; e += 256)
    atomicAdd(&cnt[((unsigned)stage[e] >> 16) & 255u], 1);
  __syncthreads();
  int v = cnt[tid];
  int lane = tid & 63, wid = tid >> 6;
  int incl = v;
  #pragma unroll
  for (int off = 1; off < 64; off <<= 1) {
    int t = __shfl_up(incl, off);
    if (lane >= off) incl += t;
  }
  if (lane == 63) wsum[wid] = incl;
  __syncthreads();
  int wpref = 0;
  #pragma unroll
  for (int w = 0; w < 4; ++w) wpref += (w < wid) ? wsum[w] : 0;
  int excl = wpref + incl - v;
  ofs[tid] = excl;
  cnt[tid] = 0;
  int n = b * 256 + tid;
  if (n < N) rowptr[n] = rbase + excl;
  if (b == gridDim.x - 1 && tid == 0) rowptr[N] = rend;
  __syncthreads();
  for (int e = rbase + tid; e < rend; e += 256) {
    unsigned p = (unsigned)stage[e];
    int j = (int)((p >> 16) & 255u);
    int pos = rbase + ofs[j] + atomicAdd(&cnt[j], 1);
    csr[pos] = p;
  }
}

// --- hierarchical scan (generic int array) ---

__global__ __launch_bounds__(256) void psum_kernel(const int* __restrict__ deg,
                                                   int* __restrict__ bsum, int n) {
  __shared__ int ws[4];
  int i = blockIdx.x * 1024 + threadIdx.x * 4;
  int4 v = make_int4(0, 0, 0, 0);
  if (i + 3 < n) v = *(const int4*)(deg + i);
  else {
    if (i < n) v.x = deg[i];
    if (i + 1 < n) v.y = deg[i + 1];
    if (i + 2 < n) v.z = deg[i + 2];
    if (i + 3 < n) v.w = deg[i + 3];
  }
  int s = v.x + v.y + v.z + v.w;
  #pragma unroll
  for (int off = 32; off; off >>= 1) s += __shfl_xor(s, off);
  int lane = threadIdx.x & 63, wid = threadIdx.x >> 6;
  if (lane == 0) ws[wid] = s;
  __syncthreads();
  if (threadIdx.x == 0) bsum[blockIdx.x] = ws[0] + ws[1] + ws[2] + ws[3];
}

__global__ __launch_bounds__(64) void bscan_kernel(int* __restrict__ bsum, int nb) {
  int lane = threadIdx.x;
  int carry = 0;
  for (int b = 0; b < nb; b += 64) {
    int i = b + lane;
    int v = (i < nb) ? bsum[i] : 0;
    int incl = v;
    #pragma unroll
    for (int off = 1; off < 64; off <<= 1) {
      int t = __shfl_up(incl, off);
      if (lane >= off) incl += t;
    }
    if (i < nb) bsum[i] = carry + incl - v;
    carry += __shfl(incl, 63);
  }
}

__global__ __launch_bounds__(256) void rowptr_kernel(const int* __restrict__ deg,
                                                     const int* __restrict__ bofs,
                                                     int* __restrict__ rowptr, int n) {
  __shared__ int ws[4];
  int i = blockIdx.x * 1024 + threadIdx.x * 4;
  int4 v = make_int4(0, 0, 0, 0);
  if (i + 3 < n) v = *(const int4*)(deg + i);
  else {
    if (i < n) v.x = deg[i];
    if (i + 1 < n) v.y = deg[i + 1];
    if (i + 2 < n) v.z = deg[i + 2];
    if (i + 3 < n) v.w = deg[i + 3];
  }
  int s = v.x + v.y + v.z + v.w;
  int lane = threadIdx.x & 63, wid = threadIdx.x >> 6;
  int incl = s;
  #pragma unroll
  for (int off = 1; off < 64; off <<= 1) {
    int t = __shfl_up(incl, off);
    if (lane >= off) incl += t;
  }
  if (lane == 63) ws[wid] = incl;
  __syncthreads();
  int wpref = 0;
  #pragma unroll
  for (int w = 0; w < 4; ++w) wpref += (w < wid) ? ws[w] : 0;
  int run = bofs[blockIdx.x] + wpref + incl - s;
  if (i < n)     { run += v.x; rowptr[i + 1] = run; }
  if (i + 1 < n) { run += v.y; rowptr[i + 2] = run; }
  if (i + 2 < n) { run += v.z; rowptr[i + 3] = run; }
  if (i + 3 < n) { run += v.w; rowptr[i + 4] = run; }
  if (blockIdx.x == 0 && threadIdx.x == 0) rowptr[0] = 0;
}

// ================= MFMA GEMM: h = bf16( (relu?)in @ W ), fused alpha =================
// 4 waves/block, wave = 16 rows x 128 cols. A-fragments straight from global fp32
// (cvt to bf16 in regs); W transposed+bf16 into swizzled LDS once per block.
// Epilogue: hb store + alpha_s/d = acc . a_s/d (fp32, pre-rounding).

template <bool RELU>
__global__ __launch_bounds__(256) void gemm_mfma_kernel(const float* __restrict__ in,
                                                        const float* __restrict__ W,
                                                        const float* __restrict__ a_s,
                                                        const float* __restrict__ a_d,
                                                        ushort* __restrict__ hb,
                                                        float* __restrict__ as_out,
                                                        float* __restrict__ ad_out, int N) {
  __shared__ ushort Wt[D * D];  // Wt[c][k] bf16, swizzled: byte = c*256 + (k*2 ^ ((c&7)<<4))
  int tid = threadIdx.x;
  // stage W^T: unit u = k-pair (64) x col-group of 4 (32)
  for (int u = tid; u < 2048; u += 256) {
    int kp = u >> 5, cg = u & 31;
    int k = kp * 2;
    float4 w0 = *(const float4*)(W + (size_t)k * D + cg * 4);
    float4 w1 = *(const float4*)(W + (size_t)(k + 1) * D + cg * 4);
    float v0[4] = {w0.x, w0.y, w0.z, w0.w};
    float v1[4] = {w1.x, w1.y, w1.z, w1.w};
    #pragma unroll
    for (int i = 0; i < 4; ++i) {
      int c = cg * 4 + i;
      unsigned word = (unsigned)bfbits(v0[i]) | ((unsigned)bfbits(v1[i]) << 16);
      int byte = c * 256 + ((k * 2) ^ ((c & 7) << 4));
      *(unsigned*)((char*)Wt + byte) = word;
    }
  }
  __syncthreads();

  int wave = tid >> 6, lane = tid & 63;
  int lrow = lane & 15, lgrp = lane >> 4;
  int r0 = blockIdx.x * 64 + wave * 16;
  int arowi = min(r0 + lrow, N - 1);  // clamp; invalid rows masked at store
  const float* arow = in + (size_t)arowi * D;

  f32x4 acc[8];
  #pragma unroll
  for (int t = 0; t < 8; ++t) acc[t] = (f32x4){0.f, 0.f, 0.f, 0.f};

  #pragma unroll
  for (int ks = 0; ks < 4; ++ks) {
    float4 a0 = *(const float4*)(arow + ks * 32 + lgrp * 8);
    float4 a1 = *(const float4*)(arow + ks * 32 + lgrp * 8 + 4);
    if (RELU) {
      a0.x = fmaxf(a0.x, 0.f); a0.y = fmaxf(a0.y, 0.f);
      a0.z = fmaxf(a0.z, 0.f); a0.w = fmaxf(a0.w, 0.f);
      a1.x = fmaxf(a1.x, 0.f); a1.y = fmaxf(a1.y, 0.f);
      a1.z = fmaxf(a1.z, 0.f); a1.w = fmaxf(a1.w, 0.f);
    }
    bf16x8 af;
    af[0] = (short)bfbits(a0.x); af[1] = (short)bfbits(a0.y);
    af[2] = (short)bfbits(a0.z); af[3] = (short)bfbits(a0.w);
    af[4] = (short)bfbits(a1.x); af[5] = (short)bfbits(a1.y);
    af[6] = (short)bfbits(a1.z); af[7] = (short)bfbits(a1.w);
    #pragma unroll
    for (int nt = 0; nt < 8; ++nt) {
      int c = nt * 16 + lrow;
      int kb = (ks * 64 + lgrp * 16) ^ ((c & 7) << 4);
      bf16x8 bfr = *(const bf16x8*)((const char*)Wt + c * 256 + kb);
      acc[nt] = __builtin_amdgcn_mfma_f32_16x16x32_bf16(af, bfr, acc[nt], 0, 0, 0);
    }
  }

  // epilogue: D[row=(lgrp*4+r)][col=nt*16+lrow] = acc[nt][r]
  float ps[4] = {0.f, 0.f, 0.f, 0.f}, pd[4] = {0.f, 0.f, 0.f, 0.f};
  #pragma unroll
  for (int nt = 0; nt < 8; ++nt) {
    float asc = a_s[nt * 16 + lrow];
    float adc = a_d[nt * 16 + lrow];
    #pragma unroll
    for (int r = 0; r < 4; ++r) {
      float v = acc[nt][r];
      ps[r] += v * asc;
      pd[r] += v * adc;
      int row = r0 + lgrp * 4 + r;
      if (row < N) hb[(size_t)row * D + nt * 16 + lrow] = bfbits(v);
    }
  }
  #pragma unroll
  for (int mk = 1; mk < 16; mk <<= 1) {
    #pragma unroll
    for (int r = 0; r < 4; ++r) {
      ps[r] += __shfl_xor(ps[r], mk);
      pd[r] += __shfl_xor(pd[r], mk);
    }
  }
  if (lrow == 0) {
    #pragma unroll
    for (int r = 0; r < 4; ++r) {
      int row = r0 + lgrp * 4 + r;
      if (row < N) { as_out[row] = ps[r]; ad_out[row] = pd[r]; }
    }
  }
}

// ================= per-edge scores =================

__global__ __launch_bounds__(256) void score_kernel(const unsigned* __restrict__ csr,
                                                    const float* __restrict__ as_,
                                                    const float* __restrict__ ad_,
                                                    float* __restrict__ escore, int total) {
  int e = blockIdx.x * 256 + threadIdx.x;
  if (e >= total) return;
  unsigned p = csr[e];
  float sc = as_[p & 0xffffu] + ad_[p >> 16];
  escore[e] = sc > 0.f ? sc : NEG_SLOPE * sc;
}

// ================= per-dst aggregation =================

__device__ inline float2 bf2_to_f2(unsigned v) {
  return make_float2(__uint_as_float(v << 16), __uint_as_float(v & 0xffff0000u));
}

__global__ __launch_bounds__(256) void agg_kernel(const unsigned* __restrict__ hb,
                                                  const int* __restrict__ rowptr,
                                                  const unsigned* __restrict__ csr,
                                                  const float* __restrict__ escore,
                                                  const float* __restrict__ bias,
                                                  float* __restrict__ out, int N) {
  int wid = threadIdx.x >> 6;
  int lane = threadIdx.x & 63;
  int n = blockIdx.x * 4 + wid;
  if (n >= N) return;
  int start = rowptr[n], end = rowptr[n + 1];

  float m = -1e30f, denom = 0.f;
  float2 acc = make_float2(0.f, 0.f);

  for (int cbase = start; cbase < end; cbase += AGG_CHUNK) {
    int cend = min(cbase + AGG_CHUNK, end);
    int cnt = cend - cbase;
    int e0 = cbase + lane, e1 = cbase + 64 + lane;
    int s0 = 0, s1 = 0;
    float sc0 = -1e30f, sc1 = -1e30f;
    if (e0 < cend) { s0 = (int)(csr[e0] & 0xffffu); sc0 = escore[e0]; }
    if (e1 < cend) { s1 = (int)(csr[e1] & 0xffffu); sc1 = escore[e1]; }
    float cm = fmaxf(sc0, sc1);
    #pragma unroll
    for (int off = 32; off; off >>= 1) cm = fmaxf(cm, __shfl_xor(cm, off));
    float mnew = fmaxf(m, cm);
    float rescale = __expf(m - mnew);
    denom *= rescale; acc.x *= rescale; acc.y *= rescale;
    m = mnew;
    float w0 = (e0 < cend) ? __expf(sc0 - m) : 0.f;
    float w1 = (e1 < cend) ? __expf(sc1 - m) : 0.f;
    float ps = w0 + w1;
    #pragma unroll
    for (int off = 32; off; off >>= 1) ps += __shfl_xor(ps, off);
    denom += ps;

    int i = 0;
    for (; i + 4 <= cnt; i += 4) {
      int   sA, sB, sC, sD_;
      float wA, wB, wC, wD_;
      if (i + 3 < 64) {
        sA = __shfl(s0, i);      wA = __shfl(w0, i);
        sB = __shfl(s0, i + 1);  wB = __shfl(w0, i + 1);
        sC = __shfl(s0, i + 2);  wC = __shfl(w0, i + 2);
        sD_ = __shfl(s0, i + 3); wD_ = __shfl(w0, i + 3);
      } else {
        sA = (i     < 64) ? __shfl(s0, i)     : __shfl(s1, i - 64);
        wA = (i     < 64) ? __shfl(w0, i)     : __shfl(w1, i - 64);
        sB = (i + 1 < 64) ? __shfl(s0, i + 1) : __shfl(s1, i - 63);
        wB = (i + 1 < 64) ? __shfl(w0, i + 1) : __shfl(w1, i - 63);
        sC = (i + 2 < 64) ? __shfl(s0, i + 2) : __shfl(s1, i - 62);
        wC = (i + 2 < 64) ? __shfl(w0, i + 2) : __shfl(w1, i - 62);
        sD_ = (i + 3 < 64) ? __shfl(s0, i + 3) : __shfl(s1, i - 61);
        wD_ = (i + 3 < 64) ? __shfl(w0, i + 3) : __shfl(w1, i - 61);
      }
      float2 hA = bf2_to_f2(hb[(size_t)sA * 64 + lane]);
      float2 hB = bf2_to_f2(hb[(size_t)sB * 64 + lane]);
      float2 hC = bf2_to_f2(hb[(size_t)sC * 64 + lane]);
      float2 hD = bf2_to_f2(hb[(size_t)sD_ * 64 + lane]);
      acc.x += wA * hA.x + wB * hB.x + wC * hC.x + wD_ * hD.x;
      acc.y += wA * hA.y + wB * hB.y + wC * hC.y + wD_ * hD.y;
    }
    for (; i < cnt; ++i) {
      int   s = (i < 64) ? __shfl(s0, i) : __shfl(s1, i - 64);
      float w = (i < 64) ? __shfl(w0, i) : __shfl(w1, i - 64);
      float2 hv = bf2_to_f2(hb[(size_t)s * 64 + lane]);
      acc.x += w * hv.x;
      acc.y += w * hv.y;
    }
  }
  float2 bv = *(const float2*)(bias + lane * 2);
  float inv = 1.f / denom;
  *(float2*)(out + (size_t)n * D + lane * 2) =
      make_float2(acc.x * inv + bv.x, acc.y * inv + bv.y);
}

// ================= launch =================

extern "C" void kernel_launch(void* const* d_in, const int* in_sizes, int n_in,
                              void* d_out, int out_size, void* d_ws, size_t ws_size,
                              hipStream_t stream) {
  const float* x   = (const float*)d_in[0];
  const int*   ei  = (const int*)d_in[1];
  const float* W1  = (const float*)d_in[2];
  const float* as1 = (const float*)d_in[3];
  const float* ad1 = (const float*)d_in[4];
  const float* b1  = (const float*)d_in[5];
  const float* W2  = (const float*)d_in[6];
  const float* as2 = (const float*)d_in[7];
  const float* ad2 = (const float*)d_in[8];
  const float* b2  = (const float*)d_in[9];

  int N = in_sizes[0] / D;        // 50000
  int E = in_sizes[1] / 2;        // 600000
  int total = E + N;
  int nbkt = (N + 255) >> 8;
  int nblk = (total + CHUNKB - 1) / CHUNKB;
  int nscan = nbkt * nblk;
  int nsb = (nscan + 1023) / 1024;

  char* ws = (char*)d_ws;
  size_t off = 0;
  auto alloc = [&](size_t bytes) {
    void* p = ws + off;
    off = (off + bytes + 255) & ~(size_t)255;
    return p;
  };
  ushort*   hb      = (ushort*)alloc((size_t)N * D * sizeof(ushort));
  float*    tmp     = (float*)alloc((size_t)N * D * sizeof(float));
  float*    alpha_s = (float*)alloc((size_t)N * sizeof(float));
  float*    alpha_d = (float*)alloc((size_t)N * sizeof(float));
  int*      rowptr  = (int*)alloc((size_t)(N + 1) * sizeof(int));
  int*      coarse  = (int*)alloc((size_t)nscan * sizeof(int));
  int*      scanout = (int*)alloc((size_t)(nscan + 1) * sizeof(int));
  int*      bsum    = (int*)alloc((size_t)(nsb + 1) * sizeof(int));
  int*      stage   = (int*)alloc((size_t)total * sizeof(int));
  unsigned* csr     = (unsigned*)alloc((size_t)total * sizeof(unsigned));
  float*    escore  = (float*)alloc((size_t)total * sizeof(float));

  int nbG = (N + 63) / 64;

  // --- CSR by dst via two-level counting sort (shared by both layers) ---
  bucket_count_kernel<<<nblk, 256, 0, stream>>>(ei, coarse, E, total, nbkt, nblk);
  psum_kernel<<<nsb, 256, 0, stream>>>(coarse, bsum, nscan);
  bscan_kernel<<<1, 64, 0, stream>>>(bsum, nsb);
  rowptr_kernel<<<nsb, 256, 0, stream>>>(coarse, bsum, scanout, nscan);
  bucket_scatter_kernel<<<nblk, 256, 0, stream>>>(ei, scanout, stage, E, total, nbkt, nblk);
  fine_sort_kernel<<<nbkt, 256, 0, stream>>>(stage, scanout, csr, rowptr, N, nblk);

  // --- layer 1 ---
  gemm_mfma_kernel<false><<<nbG, 256, 0, stream>>>(x, W1, as1, ad1, hb, alpha_s, alpha_d, N);
  score_kernel<<<(total + 255) / 256, 256, 0, stream>>>(csr, alpha_s, alpha_d, escore, total);
  agg_kernel<<<(N + 3) / 4, 256, 0, stream>>>((const unsigned*)hb, rowptr, csr, escore, b1, tmp, N);

  // --- layer 2 (relu fused into A-fragment loads) ---
  gemm_mfma_kernel<true><<<nbG, 256, 0, stream>>>(tmp, W2, as2, ad2, hb, alpha_s, alpha_d, N);
  score_kernel<<<(total + 255) / 256, 256, 0, stream>>>(csr, alpha_s, alpha_d, escore, total);
  agg_kernel<<<(N + 3) / 4, 256, 0, stream>>>((const unsigned*)hb, rowptr, csr, escore, b2, (float*)d_out, N);
}